// Round 11
// baseline (93.788 us; speedup 1.0000x reference)
//
#include <hip/hip_runtime.h>
#include <math.h>
#include <stdint.h>

#define HIDDEN 4096
#define NEXP   64
#define TOKS   64                 // tokens per main block
#define NS     32                 // 32-k steps per wave (K-slice 1024)

typedef __bf16 bf16x8 __attribute__((ext_vector_type(8)));
typedef float  f32x4  __attribute__((ext_vector_type(4)));

union BfU { uint4 u; bf16x8 b; };

// fp32 -> (hi, lo) bf16 split; dropped lo*lo term ~2^-18 rel (R8-R10 verified).
static __device__ __forceinline__ void cvt_hilo(const float* x8, bf16x8& hi, bf16x8& lo) {
#pragma unroll
    for (int j = 0; j < 8; ++j) {
        const float x = x8[j];
        const __bf16 h = (__bf16)x;
        const float  r = x - (float)h;
        hi[j] = h;
        lo[j] = (__bf16)r;
    }
}

// async global->LDS, 16B/lane, wave-uniform dest base + lane*16
__device__ __forceinline__ void gload_lds16(const void* g, void* l) {
    __builtin_amdgcn_global_load_lds(
        (const __attribute__((address_space(1))) void*)g,
        (__attribute__((address_space(3))) void*)l, 16, 0, 0);
}

// ---- pre-kernel (R8-R10 verified): W fp32 -> B-fragment-ordered bf16 hi/lo.
// Fragment F = S*4 + e (S = k-step of 32): lane l supplies
// B[col 16e+(l&15)][k 32S+8(l>>4)+j] at ws[F*512 + l*8].
__global__ __launch_bounds__(512) void wconv_kernel(
    const float* __restrict__ W, ushort* __restrict__ wsHi, ushort* __restrict__ wsLo)
{
    const int gid = blockIdx.x * 512 + threadIdx.x;   // 0..32767
    const int S = gid >> 8;
    const int e = (gid >> 6) & 3;
    const int l = gid & 63;
    const int row = 16 * e + (l & 15);
    const int k0  = 32 * S + 8 * (l >> 4);
    const float* src = W + (size_t)row * HIDDEN + k0;
    float x8[8];
    *(float4*)&x8[0] = *(const float4*)src;
    *(float4*)&x8[4] = *(const float4*)(src + 4);
    BfU hi, lo;
    cvt_hilo(x8, hi.b, lo.b);
    const size_t o = ((size_t)(S * 4 + e) * 64 + l) * 8;
    *(uint4*)(wsHi + o) = hi.u;
    *(uint4*)(wsLo + o) = lo.u;
}

// ---- main: bf16x3 MFMA router, fully per-wave pipelined, ZERO main-loop
// barriers. R10 post-mortem: per-chunk vmcnt(0)+16-wave barrier capped HBM
// duty at ~75% (1 block/CU: nothing runs during the drain). R11: wave
// (tg,kh) owns tokens [16tg,+16) x k [1024kh,+1024) in 32-k steps; stages
// its OWN 2KB X step (2 gload_lds, 8 rows x 128B each = whole cache lines)
// into a private 4-slot LDS ring; B frags to double-buffered regs from the
// fragment-ordered ws (L1-shared across the 4 tg-waves). Issue-order queue
// [X(s)2, B(s)8, X(s+1)2] + counted vmcnt(2) -> X(s+1) never drained (T4).
// Intra-row granule XOR (l&7)^((l>>3)&7) keeps ds_read_b128 at the 8-cyc
// throughput floor. 4 K-split partials combined in the verified epilogue.
__global__ __launch_bounds__(1024, 1) void router_mfma_kernel(
    const float* __restrict__ X,
    const ushort* __restrict__ wsHi, const ushort* __restrict__ wsLo,
    const float* __restrict__ Bv, float* __restrict__ out, int nTok)
{
    __shared__ float smem[32768];   // 128 KiB: 16 waves x 4-slot ring x 2KB

    const int tid = threadIdx.x;
    const int wv  = __builtin_amdgcn_readfirstlane(tid >> 6);
    const int tg  = wv >> 2;        // token-group 0..3
    const int kh  = wv & 3;         // K-split 0..3
    const int l   = tid & 63;
    const int g   = l >> 4;         // k-slot group 0..3
    const int cr  = l & 15;         // A row / B col within tile
    const int t0  = blockIdx.x * TOKS;

    // X staging: instr r covers rows 8r..8r+7 (lane l -> row 8r+(l>>3)),
    // dest granule l&7, source granule (l&7)^((l>>3)&7) (involution).
    const float* XgS[2];
#pragma unroll
    for (int r = 0; r < 2; ++r) {
        const int row = 8 * r + (l >> 3);
        const int sg  = (l & 7) ^ ((l >> 3) & 7);
        XgS[r] = X + (size_t)(t0 + 16 * tg + row) * HIDDEN + kh * 1024 + sg * 4;
    }
    float* const wreg = smem + wv * 2048;    // 4 slots x 512 floats

    // B frag base for step s: + s*2048 ushorts (frag = (32kh+s)*4 + e)
    const ushort* const wh0 = wsHi + (size_t)(kh * 32) * 2048 + (size_t)l * 8;
    const ushort* const wl0 = wsLo + (size_t)(kh * 32) * 2048 + (size_t)l * 8;

    // A-frag read offsets within a slot: row cr, granules (2g+h)^(cr&7)
    const int m8   = cr & 7;
    const int rdA0 = cr * 32 + 4 * ((2 * g + 0) ^ m8);
    const int rdA1 = cr * 32 + 4 * ((2 * g + 1) ^ m8);

    f32x4 acc[4] = {{0.f,0.f,0.f,0.f},{0.f,0.f,0.f,0.f},{0.f,0.f,0.f,0.f},{0.f,0.f,0.f,0.f}};
    uint4 bhA[4], blA[4], bhB[4], blB[4];

    // prologue: queue = [X(0)2, B(0)8, X(1)2]
    gload_lds16(XgS[0], wreg);
    gload_lds16(XgS[1], wreg + 256);
#pragma unroll
    for (int e = 0; e < 4; ++e) {
        bhA[e] = *(const uint4*)(wh0 + e * 512);
        blA[e] = *(const uint4*)(wl0 + e * 512);
    }
    gload_lds16(XgS[0] + 32, wreg + 512);
    gload_lds16(XgS[1] + 32, wreg + 512 + 256);

#pragma unroll 1
    for (int sp = 0; sp < NS; sp += 2) {
        // ---- step s = sp (even, consumes setA) ----
        asm volatile("s_waitcnt vmcnt(2)" ::: "memory");   // X(s),B(s) done; X(s+1) in flight
        {
            const ushort* wh = wh0 + (size_t)(sp + 1) * 2048;
            const ushort* wl = wl0 + (size_t)(sp + 1) * 2048;
#pragma unroll
            for (int e = 0; e < 4; ++e) {
                bhB[e] = *(const uint4*)(wh + e * 512);
                blB[e] = *(const uint4*)(wl + e * 512);
            }
        }
        if (sp + 2 < NS) {
            float* d = wreg + ((sp + 2) & 3) * 512;
            gload_lds16(XgS[0] + (sp + 2) * 32, d);
            gload_lds16(XgS[1] + (sp + 2) * 32, d + 256);
        }
        {
            const float* xb = wreg + (sp & 3) * 512;
            float x8[8];
            *(float4*)&x8[0] = *(const float4*)(xb + rdA0);
            *(float4*)&x8[4] = *(const float4*)(xb + rdA1);
            bf16x8 xh, xo; cvt_hilo(x8, xh, xo);
#pragma unroll
            for (int e = 0; e < 4; ++e) {
                BfU ph, pl; ph.u = bhA[e]; pl.u = blA[e];
                acc[e] = __builtin_amdgcn_mfma_f32_16x16x32_bf16(xh, ph.b, acc[e], 0, 0, 0);
                acc[e] = __builtin_amdgcn_mfma_f32_16x16x32_bf16(xo, ph.b, acc[e], 0, 0, 0);
                acc[e] = __builtin_amdgcn_mfma_f32_16x16x32_bf16(xh, pl.b, acc[e], 0, 0, 0);
            }
        }
        // ---- step s = sp+1 (odd, consumes setB) ----
        asm volatile("s_waitcnt vmcnt(2)" ::: "memory");
        if (sp + 2 < NS) {
            const ushort* wh = wh0 + (size_t)(sp + 2) * 2048;
            const ushort* wl = wl0 + (size_t)(sp + 2) * 2048;
#pragma unroll
            for (int e = 0; e < 4; ++e) {
                bhA[e] = *(const uint4*)(wh + e * 512);
                blA[e] = *(const uint4*)(wl + e * 512);
            }
        }
        if (sp + 3 < NS) {
            float* d = wreg + ((sp + 3) & 3) * 512;
            gload_lds16(XgS[0] + (sp + 3) * 32, d);
            gload_lds16(XgS[1] + (sp + 3) * 32, d + 256);
        }
        {
            const float* xb = wreg + ((sp + 1) & 3) * 512;
            float x8[8];
            *(float4*)&x8[0] = *(const float4*)(xb + rdA0);
            *(float4*)&x8[4] = *(const float4*)(xb + rdA1);
            bf16x8 xh, xo; cvt_hilo(x8, xh, xo);
#pragma unroll
            for (int e = 0; e < 4; ++e) {
                BfU ph, pl; ph.u = bhB[e]; pl.u = blB[e];
                acc[e] = __builtin_amdgcn_mfma_f32_16x16x32_bf16(xh, ph.b, acc[e], 0, 0, 0);
                acc[e] = __builtin_amdgcn_mfma_f32_16x16x32_bf16(xo, ph.b, acc[e], 0, 0, 0);
                acc[e] = __builtin_amdgcn_mfma_f32_16x16x32_bf16(xh, pl.b, acc[e], 0, 0, 0);
            }
        }
    }

    __syncthreads();   // drains all counters; safe to alias LDS

    // ---- epilogue (R8-R10 verified), LDS aliased: tiles 69632B + tt 16640B
    float (*tiles)[64][68] = (float (*)[64][68])smem;
    float* tt = smem + 4 * 64 * 68;

    // C/D layout (m89): row = 16tg + 4g + i, col = 16e + cr
#pragma unroll
    for (int e = 0; e < 4; ++e)
#pragma unroll
        for (int i = 0; i < 4; ++i)
            tiles[kh][16 * tg + 4 * g + i][16 * e + cr] = acc[e][i];
    __syncthreads();

    const size_t offSel = (size_t)nTok * 2;
    const size_t offLog = (size_t)nTok * 4;

    // combine 4 K-split partials + bias; store logits; build transposed tile
    {
        const int tok = tid >> 4;          // 0..63
        const int e4  = (tid & 15) * 4;
        const float4 s0 = *(const float4*)&tiles[0][tok][e4];
        const float4 s1 = *(const float4*)&tiles[1][tok][e4];
        const float4 s2 = *(const float4*)&tiles[2][tok][e4];
        const float4 s3 = *(const float4*)&tiles[3][tok][e4];
        const float4 bb = *(const float4*)(Bv + e4);
        const float4 r = make_float4(s0.x + s1.x + s2.x + s3.x + bb.x,
                                     s0.y + s1.y + s2.y + s3.y + bb.y,
                                     s0.z + s1.z + s2.z + s3.z + bb.z,
                                     s0.w + s1.w + s2.w + s3.w + bb.w);
        *(float4*)(out + offLog + (size_t)(t0 + tok) * NEXP + e4) = r;
        tt[(e4 + 0) * 65 + tok] = r.x;
        tt[(e4 + 1) * 65 + tok] = r.y;
        tt[(e4 + 2) * 65 + tok] = r.z;
        tt[(e4 + 3) * 65 + tok] = r.w;
    }
    __syncthreads();

    // top-2 + softmax (verified): strict > keeps lowest index on ties
    if (tid < 64) {
        const int t = tid;
        float m1 = -INFINITY, m2 = -INFINITY;
        int i1 = 0, i2 = 0;
#pragma unroll
        for (int e = 0; e < NEXP; ++e) {
            const float v = tt[e * 65 + t];
            if (v > m1)      { m2 = m1; i2 = i1; m1 = v; i1 = e; }
            else if (v > m2) { m2 = v; i2 = e; }
        }
        const float ex  = expf(m2 - m1);
        const float inv = 1.0f / (1.0f + ex);
        *(float2*)(out + (size_t)(t0 + t) * 2)          = make_float2(inv, ex * inv);
        *(float2*)(out + offSel + (size_t)(t0 + t) * 2) = make_float2((float)i1, (float)i2);
    }

    if (blockIdx.x == 0 && tid == 0)
        out[offLog + (size_t)nTok * NEXP] = 0.0f;   // aux_loss
}

extern "C" void kernel_launch(void* const* d_in, const int* in_sizes, int n_in,
                              void* d_out, int out_size, void* d_ws, size_t ws_size,
                              hipStream_t stream)
{
    const float* X  = (const float*)d_in[0];
    const float* W  = (const float*)d_in[1];
    const float* Bv = (const float*)d_in[2];
    float* out = (float*)d_out;
    const int nTok = in_sizes[0] / HIDDEN;    // 16384
    ushort* wsHi = (ushort*)d_ws;             // 512 KB
    ushort* wsLo = wsHi + (size_t)NEXP * HIDDEN;  // 512 KB

    wconv_kernel<<<64, 512, 0, stream>>>(W, wsHi, wsLo);
    router_mfma_kernel<<<nTok / TOKS, 1024, 0, stream>>>(X, wsHi, wsLo, Bv, out, nTok);
}

// Round 12
// 84.699 us; speedup vs baseline: 1.1073x; 1.1073x over previous
//
#include <hip/hip_runtime.h>
#include <math.h>
#include <stdint.h>

#define HIDDEN 4096
#define NEXP   64
#define TOKS   32                 // tokens per main block
#define KCH    64                 // k floats per staged chunk
#define NCHK   (HIDDEN / KCH)     // 64 chunks
#define X_FL   (TOKS * KCH)       // 2048 floats: X region (8 KB)
#define PAR_FL (X_FL + 2 * 2048)  // + Bhi 8KB + Blo 8KB = 6144 floats (24 KB)

typedef __bf16 bf16x8 __attribute__((ext_vector_type(8)));
typedef float  f32x4  __attribute__((ext_vector_type(4)));

union BfU { uint4 u; bf16x8 b; };

// fp32 -> (hi, lo) bf16 split; dropped lo*lo term ~2^-18 rel (R8-R10 verified).
static __device__ __forceinline__ void cvt_hilo(const float* x8, bf16x8& hi, bf16x8& lo) {
#pragma unroll
    for (int j = 0; j < 8; ++j) {
        const float x = x8[j];
        const __bf16 h = (__bf16)x;
        const float  r = x - (float)h;
        hi[j] = h;
        lo[j] = (__bf16)r;
    }
}

// async global->LDS, 16B/lane, wave-uniform dest base + lane*16
__device__ __forceinline__ void gload_lds16(const void* g, void* l) {
    __builtin_amdgcn_global_load_lds(
        (const __attribute__((address_space(1))) void*)g,
        (__attribute__((address_space(3))) void*)l, 16, 0, 0);
}

// ---- pre-kernel (R8-R10 verified; now grid 256x128 -> all CUs busy):
// W fp32 -> B-fragment-ordered bf16 hi/lo. Fragment F = S*4 + e (S = k-step
// of 32): lane l supplies B[col 16e+(l&15)][k 32S+8(l>>4)+j] at ws[F*512+l*8].
__global__ __launch_bounds__(512) void wconv_kernel(
    const float* __restrict__ W, ushort* __restrict__ wsHi, ushort* __restrict__ wsLo)
{
    const int gid = blockIdx.x * blockDim.x + threadIdx.x;   // 0..32767
    const int S = gid >> 8;
    const int e = (gid >> 6) & 3;
    const int l = gid & 63;
    const int row = 16 * e + (l & 15);
    const int k0  = 32 * S + 8 * (l >> 4);
    const float* src = W + (size_t)row * HIDDEN + k0;
    float x8[8];
    *(float4*)&x8[0] = *(const float4*)src;
    *(float4*)&x8[4] = *(const float4*)(src + 4);
    BfU hi, lo;
    cvt_hilo(x8, hi.b, lo.b);
    const size_t o = ((size_t)(S * 4 + e) * 64 + l) * 8;
    *(uint4*)(wsHi + o) = hi.u;
    *(uint4*)(wsLo + o) = lo.u;
}

// ---- main: bf16x3 MFMA router, R10 structure at HALF block size so TWO
// independent blocks co-reside per CU (grid 512, LDS 48KB/block). R10's
// residual loss was the 1-block/CU sync convoy: per chunk all 16 waves wait
// on the slowest stage (max-of-16) and HBM goes idle across the barrier.
// With 2 blocks/CU the other block's issue/compute covers those windows.
// 8 waves = tg(2) x eh(2) x kh(2): wave = 16 tok x 32 exp x one 32-k step
// per 64-k chunk. Per chunk per wave: 1 X gload_lds + 1 Bhi + 1 Blo (B's
// 8-frag ws window is contiguous -> linear staging), then 6 ds_read_b128 +
// 6 MFMA. X source-granule XOR involution (rule #21) => reads <=2-way.
__global__ __launch_bounds__(512, 2) void router_mfma_kernel(
    const float* __restrict__ X,
    const ushort* __restrict__ wsHi, const ushort* __restrict__ wsLo,
    const float* __restrict__ Bv, float* __restrict__ out, int nTok)
{
    __shared__ float smem[2 * PAR_FL];   // 49152 B; epilogue aliases

    const int tid = threadIdx.x;
    const int wv  = tid >> 6;        // 0..7
    const int tg  = wv >> 2;         // token-group 0..1 (16 tokens each)
    const int eh  = (wv >> 1) & 1;   // expert-half 0..1 (32 experts each)
    const int kh  = wv & 1;          // k-step within chunk 0..1
    const int l   = tid & 63;
    const int g   = l >> 4;          // k-slot group 0..3
    const int cr  = l & 15;          // A row / B col within tile
    const int t0  = blockIdx.x * TOKS;

    // X staging: instr (one per wave) covers rows 4wv..4wv+3 (lane l ->
    // row 4wv+(l>>4), dest granule l&15). Source granule = (l&8)|((l&7)^(row&7))
    // (involution) so fragment-order reads land <=2-way banked.
    const int srow = 4 * wv + (l >> 4);
    const int sgr  = (l & 8) | ((l & 7) ^ (srow & 7));
    const float* XgS = X + (size_t)(t0 + srow) * HIDDEN + sgr * 4;
    const int xdst  = wv * 256;                 // floats (uniform base)
    // B staging: chunk window = frags [8c, 8c+8) (contiguous 8KB per plane);
    // wave wv stages frag wv (1KB, lane-linear).
    const ushort* BhS = wsHi + (size_t)wv * 512 + (size_t)l * 8;
    const ushort* BlS = wsLo + (size_t)wv * 512 + (size_t)l * 8;
    const int bhdst = X_FL + wv * 256;
    const int bldst = X_FL + 2048 + wv * 256;

    // A-frag read: row 16tg+cr, global granule q = 8kh+2g+h stored at
    // position 8kh | ((2g+h)^(cr&7)).
    const int m8   = cr & 7;
    const int rowX = (16 * tg + cr) * KCH;
    const int rdA0 = rowX + 4 * (8 * kh + ((2 * g + 0) ^ m8));
    const int rdA1 = rowX + 4 * (8 * kh + ((2 * g + 1) ^ m8));

    f32x4 acc[2] = {{0.f,0.f,0.f,0.f},{0.f,0.f,0.f,0.f}};

    // prologue: stage chunk 0 -> parity 0
    gload_lds16(XgS, smem + xdst);
    gload_lds16(BhS, smem + bhdst);
    gload_lds16(BlS, smem + bldst);

#pragma unroll 1
    for (int c = 0; c < NCHK; ++c) {
        asm volatile("s_waitcnt vmcnt(0)" ::: "memory");   // my 3 stages for c done
        __syncthreads();                                   // chunk c visible (drain free)
        const int p = c & 1;
        if (c + 1 < NCHK) {                                // issue c+1 -> other parity
            float* pb = smem + ((c + 1) & 1) * PAR_FL;
            gload_lds16(XgS + (c + 1) * KCH, pb + xdst);
            gload_lds16(BhS + (size_t)(c + 1) * 4096, pb + bhdst);
            gload_lds16(BlS + (size_t)(c + 1) * 4096, pb + bldst);
        }
        const float*  xb = smem + p * PAR_FL;
        const ushort* bh = (const ushort*)(smem + p * PAR_FL + X_FL) + kh * 2048 + l * 8;
        const ushort* bl = bh + 4096;                      // Blo region (+8KB)
        float x8[8];
        *(float4*)&x8[0] = *(const float4*)(xb + rdA0);
        *(float4*)&x8[4] = *(const float4*)(xb + rdA1);
        bf16x8 xh, xo; cvt_hilo(x8, xh, xo);
#pragma unroll
        for (int e = 0; e < 2; ++e) {
            const int e2 = 2 * eh + e;
            BfU ph, pl;
            ph.u = *(const uint4*)(bh + e2 * 512);
            pl.u = *(const uint4*)(bl + e2 * 512);
            acc[e] = __builtin_amdgcn_mfma_f32_16x16x32_bf16(xh, ph.b, acc[e], 0, 0, 0);
            acc[e] = __builtin_amdgcn_mfma_f32_16x16x32_bf16(xo, ph.b, acc[e], 0, 0, 0);
            acc[e] = __builtin_amdgcn_mfma_f32_16x16x32_bf16(xh, pl.b, acc[e], 0, 0, 0);
        }
    }

    __syncthreads();   // all reads done; safe to alias LDS for epilogue

    // ---- epilogue: kh-combine via LDS tiles [2][32][68] + transposed top-2
    float (*tiles)[32][68] = (float (*)[32][68])smem;   // 4352 floats
    float* tt = smem + 4608;                            // 64*33 = 2112 floats

    // C/D layout (m89): row = 16tg + 4g + i, col = 16e2 + cr
#pragma unroll
    for (int e = 0; e < 2; ++e) {
        const int e2 = 2 * eh + e;
#pragma unroll
        for (int i = 0; i < 4; ++i)
            tiles[kh][16 * tg + 4 * g + i][16 * e2 + cr] = acc[e][i];
    }
    __syncthreads();

    const size_t offSel = (size_t)nTok * 2;
    const size_t offLog = (size_t)nTok * 4;

    // combine 2 kh-partials + bias; store logits; build transposed tile
    {
        const int tok = tid >> 4;          // 0..31
        const int e4  = (tid & 15) * 4;
        const float4 s0 = *(const float4*)&tiles[0][tok][e4];
        const float4 s1 = *(const float4*)&tiles[1][tok][e4];
        const float4 bb = *(const float4*)(Bv + e4);
        const float4 r = make_float4(s0.x + s1.x + bb.x, s0.y + s1.y + bb.y,
                                     s0.z + s1.z + bb.z, s0.w + s1.w + bb.w);
        *(float4*)(out + offLog + (size_t)(t0 + tok) * NEXP + e4) = r;
        tt[(e4 + 0) * 33 + tok] = r.x;
        tt[(e4 + 1) * 33 + tok] = r.y;
        tt[(e4 + 2) * 33 + tok] = r.z;
        tt[(e4 + 3) * 33 + tok] = r.w;
    }
    __syncthreads();

    // top-2 + softmax (verified): strict > keeps lowest index on ties
    if (tid < TOKS) {
        const int t = tid;
        float m1 = -INFINITY, m2 = -INFINITY;
        int i1 = 0, i2 = 0;
#pragma unroll
        for (int e = 0; e < NEXP; ++e) {
            const float v = tt[e * 33 + t];
            if (v > m1)      { m2 = m1; i2 = i1; m1 = v; i1 = e; }
            else if (v > m2) { m2 = v; i2 = e; }
        }
        const float ex  = expf(m2 - m1);
        const float inv = 1.0f / (1.0f + ex);
        *(float2*)(out + (size_t)(t0 + t) * 2)          = make_float2(inv, ex * inv);
        *(float2*)(out + offSel + (size_t)(t0 + t) * 2) = make_float2((float)i1, (float)i2);
    }

    if (blockIdx.x == 0 && tid == 0)
        out[offLog + (size_t)nTok * NEXP] = 0.0f;   // aux_loss
}

extern "C" void kernel_launch(void* const* d_in, const int* in_sizes, int n_in,
                              void* d_out, int out_size, void* d_ws, size_t ws_size,
                              hipStream_t stream)
{
    const float* X  = (const float*)d_in[0];
    const float* W  = (const float*)d_in[1];
    const float* Bv = (const float*)d_in[2];
    float* out = (float*)d_out;
    const int nTok = in_sizes[0] / HIDDEN;    // 16384
    ushort* wsHi = (ushort*)d_ws;             // 512 KB
    ushort* wsLo = wsHi + (size_t)NEXP * HIDDEN;  // 512 KB

    wconv_kernel<<<256, 128, 0, stream>>>(W, wsHi, wsLo);
    router_mfma_kernel<<<nTok / TOKS, 512, 0, stream>>>(X, wsHi, wsLo, Bv, out, nTok);
}